// Round 9
// baseline (71.480 us; speedup 1.0000x reference)
//
#include <hip/hip_runtime.h>

// Binary successive-approximation encoder:
//   v = clip(x,0,1); bit i of floor(v*2^n) (clamped to 2^n-1) reproduces the
//   reference's successive subtraction exactly (all pow2 ops exact in fp32).
// x: [16,1024,512] f32 -> out: [16,1024,n_bits,512] f32.
//
// R9 = R6 phase-batching + R8 nontemporal stores.
// R8 proved stores must be nt: normal stores reach DRAM in L2-eviction order,
// which destroyed every issue-order optimization (R5-R7). With nt stores the
// issue order finally survives to the memory controller, so R6's read/write
// phase batching (which was laundered away by L2 before) gets a real test:
// each block = 16 consecutive rows; phase 1 = 16 loads/thread (16KB read
// burst per wave), phase 2 = 80 nt stores/thread (80KB write burst per wave),
// globally monotone. Targets DRAM read<->write turnaround, the remaining gap
// to the 6.29 TB/s mixed ceiling (m13).
//
// Thread map within a row (R5): c4 = tid&127 -> input float4, bit0 = tid>>7 ->
// bit parity; output float4 slot k*256+tid == (2k+bit0)*128 + c4.

#define C_DIM 512
#define C4    128   // C_DIM / 4
#define ROWS   16   // rows per block (16384 % 16 == 0)

typedef float f32x4 __attribute__((ext_vector_type(4)));

__global__ __launch_bounds__(256) void binenc_kernel(const float* __restrict__ x,
                                                     const int* __restrict__ n_bits_p,
                                                     float* __restrict__ out,
                                                     int n_rows) {
    const int n_bits = *n_bits_p;
    const float scale = (float)(1u << n_bits);
    const int   maxq  = (1 << n_bits) - 1;

    const int tid  = threadIdx.x;
    const int c4   = tid & (C4 - 1);
    const int bit0 = tid >> 7;
    const int g    = blockIdx.x * ROWS;

    if (g + ROWS <= n_rows) {
        // Phase 1: read burst — 16 independent cached loads per thread.
        f32x4 xv[ROWS];
#pragma unroll
        for (int r = 0; r < ROWS; ++r)
            xv[r] = reinterpret_cast<const f32x4*>(x)[(size_t)(g + r) * C4 + c4];

        // Quantize all rows (VALU only, no memory).
        int q[ROWS][4];
#pragma unroll
        for (int r = 0; r < ROWS; ++r) {
#pragma unroll
            for (int j = 0; j < 4; ++j) {
                float v  = fminf(fmaxf(xv[r][j], 0.0f), 1.0f);  // jnp.clip, exact
                int   qi = (int)(v * scale);                    // exact pow2 scale+trunc
                q[r][j] = qi > maxq ? maxq : qi;                // v==1.0 -> all bits
            }
        }

        // Phase 2: nt write burst — 80 stores/thread, byte-monotone per block.
#pragma unroll
        for (int r = 0; r < ROWS; ++r) {
            f32x4* rowbase = reinterpret_cast<f32x4*>(out) + (size_t)(g + r) * n_bits * C4;
#pragma unroll 5
            for (int k = 0; 2 * k + bit0 < n_bits; ++k) {
                const int sh = n_bits - 1 - (2 * k + bit0);
                f32x4 s;
#pragma unroll
                for (int j = 0; j < 4; ++j)
                    s[j] = (float)((q[r][j] >> sh) & 1);
                __builtin_nontemporal_store(s, rowbase + k * 256 + tid);
            }
        }
    } else {
        // Guarded tail (unused for 16384 rows, kept for generality).
        for (int r = 0; r < ROWS && g + r < n_rows; ++r) {
            const f32x4 xv = reinterpret_cast<const f32x4*>(x)[(size_t)(g + r) * C4 + c4];
            int q[4];
#pragma unroll
            for (int j = 0; j < 4; ++j) {
                float v  = fminf(fmaxf(xv[j], 0.0f), 1.0f);
                int   qi = (int)(v * scale);
                q[j] = qi > maxq ? maxq : qi;
            }
            f32x4* rowbase = reinterpret_cast<f32x4*>(out) + (size_t)(g + r) * n_bits * C4;
            for (int k = 0; 2 * k + bit0 < n_bits; ++k) {
                const int sh = n_bits - 1 - (2 * k + bit0);
                f32x4 s;
#pragma unroll
                for (int j = 0; j < 4; ++j)
                    s[j] = (float)((q[j] >> sh) & 1);
                __builtin_nontemporal_store(s, rowbase + k * 256 + tid);
            }
        }
    }
}

extern "C" void kernel_launch(void* const* d_in, const int* in_sizes, int n_in,
                              void* d_out, int out_size, void* d_ws, size_t ws_size,
                              hipStream_t stream) {
    const float* x        = (const float*)d_in[0];
    const int*   n_bits_p = (const int*)d_in[1];
    float*       out      = (float*)d_out;

    const int n_rows = in_sizes[0] / C_DIM;            // 16*1024 = 16384
    const int grid   = (n_rows + ROWS - 1) / ROWS;     // 1024 blocks
    const int block  = 256;

    binenc_kernel<<<grid, block, 0, stream>>>(x, n_bits_p, out, n_rows);
}

// Round 10
// 64.510 us; speedup vs baseline: 1.1081x; 1.1081x over previous
//
#include <hip/hip_runtime.h>

// Binary successive-approximation encoder:
//   v = clip(x,0,1); bit i of floor(v*2^n) (clamped to 2^n-1) reproduces the
//   reference's successive subtraction exactly (all pow2 ops exact in fp32).
// x: [16,1024,512] f32 -> out: [16,1024,n_bits,512] f32.
//
// R10 = revert to R8 (best: 64.6 us, 5.7 TB/s aggregate = 91% of the measured
// 6.29 TB/s mixed-stream ceiling). R9's 16-row phase batching regressed
// (71.5 us): 80 back-to-back nt stores per thread stall the store queue.
// Mechanism ledger:
//   - nt stores: +12% (normal stores reach DRAM in L2-eviction order; nt
//     preserves issue order to the memory controller)  [R8, confirmed]
//   - issue-order/MLP/occupancy/dispatch-shape/interleave-grain/turnaround
//     batching: all falsified (R1,R3,R4,R5,R6,R7,R9)
// Remaining ~9% gap ~ fixed ramp/drain (~5us) unamortizable at 65us scale.
//
// Thread map: block = row (b*T+t), 256 thr; c4 = tid&127 picks the input
// float4, bit0 = tid>>7 picks bit parity; output float4 slot k*256+tid ==
// (2k+bit0)*128 + c4 -> stores walk the row byte-sequentially as k increases.

#define C_DIM 512
#define C4    128   // C_DIM / 4

typedef float f32x4 __attribute__((ext_vector_type(4)));

__global__ __launch_bounds__(256) void binenc_kernel(const float* __restrict__ x,
                                                     const int* __restrict__ n_bits_p,
                                                     float* __restrict__ out) {
    const int n_bits = *n_bits_p;
    const float scale = (float)(1u << n_bits);
    const int   maxq  = (1 << n_bits) - 1;

    const int row  = blockIdx.x;
    const int tid  = threadIdx.x;
    const int c4   = tid & (C4 - 1);   // input float4 within the row
    const int bit0 = tid >> 7;         // bit parity this thread writes

    // Cached load: 33.5 MB input is L3-resident across graph replays.
    const f32x4 xv = reinterpret_cast<const f32x4*>(x)[row * C4 + c4];

    int q[4];
#pragma unroll
    for (int j = 0; j < 4; ++j) {
        float v  = fminf(fmaxf(xv[j], 0.0f), 1.0f);   // jnp.clip, exact
        int   qi = (int)(v * scale);                  // exact pow2 scale + trunc
        q[j] = qi > maxq ? maxq : qi;                 // v==1.0 -> all bits set
    }

    f32x4* rowbase = reinterpret_cast<f32x4*>(out) + (size_t)row * n_bits * C4;
#pragma unroll 5
    for (int k = 0; 2 * k + bit0 < n_bits; ++k) {
        const int sh = n_bits - 1 - (2 * k + bit0);
        f32x4 s;
#pragma unroll
        for (int j = 0; j < 4; ++j)
            s[j] = (float)((q[j] >> sh) & 1);
        __builtin_nontemporal_store(s, rowbase + k * 256 + tid);
    }
}

extern "C" void kernel_launch(void* const* d_in, const int* in_sizes, int n_in,
                              void* d_out, int out_size, void* d_ws, size_t ws_size,
                              hipStream_t stream) {
    const float* x        = (const float*)d_in[0];
    const int*   n_bits_p = (const int*)d_in[1];
    float*       out      = (float*)d_out;

    const int n_rows = in_sizes[0] / C_DIM;   // 16*1024 = 16384 rows
    const int block  = 256;

    binenc_kernel<<<n_rows, block, 0, stream>>>(x, n_bits_p, out);
}